// Round 1
// baseline (2662.094 us; speedup 1.0000x reference)
//
#include <hip/hip_runtime.h>

#define BB 64
#define TT 1024
#define DD 256
#define HH 256

// tanh(x) = 1 - 2/(e^{2x}+1); handles +-inf saturation correctly.
__device__ __forceinline__ float fast_tanh(float x) {
    float e = __expf(2.0f * x);
    return 1.0f - 2.0f / (e + 1.0f);
}

// ---------------------------------------------------------------------------
// Phase 1: xp[b][t][j] = sum_d x[b][t][d] * W_ih[j][d] + b_ih[j]
// Grid: 256 WGs (batch * 4 t-slices), 1024 threads.
// Thread (j = tid>>2, c = tid&3) holds W_ih[j][64c..64c+63] in registers.
// x row reads are 4-distinct-address broadcasts -> L1-served.
// 4-way k reduction via in-wave shfl_xor. No barriers at all.
// ---------------------------------------------------------------------------
__global__ __launch_bounds__(1024) void xproj_kernel(
    const float* __restrict__ x, const float* __restrict__ W_ih,
    const float* __restrict__ b_ih, float* __restrict__ xp)
{
    const int tid = threadIdx.x;
    const int j = tid >> 2;   // 0..255 output unit
    const int c = tid & 3;    // 0..3 k-chunk
    const int b  = blockIdx.x >> 2;
    const int t0 = (blockIdx.x & 3) * 256;

    float w[64];
    const float* wp = W_ih + j * DD + c * 64;
    #pragma unroll
    for (int i = 0; i < 16; ++i) {
        const float4 v = *(const float4*)(wp + 4 * i);
        w[4*i+0] = v.x; w[4*i+1] = v.y; w[4*i+2] = v.z; w[4*i+3] = v.w;
    }
    const float bias = b_ih[j];

    const float* xrow = x + (size_t)b * TT * DD + (size_t)t0 * DD + c * 64;
    float* xpo = xp + (size_t)b * TT * HH + (size_t)t0 * HH + j;

    for (int tt = 0; tt < 256; ++tt) {
        const float* xr = xrow + tt * DD;
        float acc = 0.0f;
        #pragma unroll
        for (int i = 0; i < 16; ++i) {
            const float4 v = *(const float4*)(xr + 4 * i);
            acc = fmaf(w[4*i+0], v.x, acc);
            acc = fmaf(w[4*i+1], v.y, acc);
            acc = fmaf(w[4*i+2], v.z, acc);
            acc = fmaf(w[4*i+3], v.w, acc);
        }
        acc += __shfl_xor(acc, 1);
        acc += __shfl_xor(acc, 2);
        if (c == 0) xpo[tt * HH] = acc + bias;
    }
}

// ---------------------------------------------------------------------------
// Phase 2: sequential recurrence, one WG per batch element (64 WGs, 1024 thr).
// h in LDS, double-buffered; chunk c stored at word offset c*68 (pad 4) so the
// 4-distinct-address ds_read_b128 broadcast is bank-conflict-free.
// io[] holds x_proj on entry and is overwritten in place with h (out).
// One __syncthreads per step; xp prefetch distance 2.
// ---------------------------------------------------------------------------
__global__ __launch_bounds__(1024) void rnn_kernel(
    const float* __restrict__ W_hh, const float* __restrict__ b_hh,
    float* __restrict__ io)
{
    const int tid = threadIdx.x;
    const int j = tid >> 2;   // 0..255 output unit
    const int c = tid & 3;    // 0..3 k-chunk
    const int b = blockIdx.x;

    __shared__ float hbuf[2][4 * 68];   // [buf][chunk*68 + pos]

    float w[64];
    const float* wp = W_hh + j * HH + c * 64;
    #pragma unroll
    for (int i = 0; i < 16; ++i) {
        const float4 v = *(const float4*)(wp + 4 * i);
        w[4*i+0] = v.x; w[4*i+1] = v.y; w[4*i+2] = v.z; w[4*i+3] = v.w;
    }
    const float bias = b_hh[j];

    if (tid < 272) hbuf[0][tid] = 0.0f;   // h_0 = 0
    __syncthreads();

    float* base = io + (size_t)b * TT * HH + j;

    // prefetch xp[0], xp[1]
    float xp0 = base[0];
    float xp1 = base[HH];

    int p = 0;
    for (int t = 0; t < TT; ++t) {
        // issue prefetch for xp[t+2] (lands during the dot phase)
        const int tn = (t + 2 < TT) ? (t + 2) : (TT - 1);
        const float xpn = base[(size_t)tn * HH];

        const float* hc = &hbuf[p][c * 68];
        float acc = 0.0f;
        #pragma unroll
        for (int i = 0; i < 16; ++i) {
            const float4 v = *(const float4*)(hc + 4 * i);
            acc = fmaf(w[4*i+0], v.x, acc);
            acc = fmaf(w[4*i+1], v.y, acc);
            acc = fmaf(w[4*i+2], v.z, acc);
            acc = fmaf(w[4*i+3], v.w, acc);
        }
        // combine the 4 k-chunks in-wave
        acc += __shfl_xor(acc, 1);
        acc += __shfl_xor(acc, 2);

        const float hn = fast_tanh(acc + xp0 + bias);
        if (c == 0) {
            hbuf[1 - p][((j >> 6) * 68) + (j & 63)] = hn;  // h for next step
            base[(size_t)t * HH] = hn;                      // output (overwrites xp[t])
        }
        xp0 = xp1;
        xp1 = xpn;
        p ^= 1;
        __syncthreads();
    }
}

extern "C" void kernel_launch(void* const* d_in, const int* in_sizes, int n_in,
                              void* d_out, int out_size, void* d_ws, size_t ws_size,
                              hipStream_t stream) {
    const float* x    = (const float*)d_in[0];
    const float* W_ih = (const float*)d_in[1];
    const float* W_hh = (const float*)d_in[2];
    const float* b_ih = (const float*)d_in[3];
    const float* b_hh = (const float*)d_in[4];
    float* out = (float*)d_out;

    // Phase 1: x_proj into d_out (aliased scratch; overwritten by phase 2).
    xproj_kernel<<<dim3(BB * 4), dim3(1024), 0, stream>>>(x, W_ih, b_ih, out);
    // Phase 2: sequential recurrence, in-place on d_out.
    rnn_kernel<<<dim3(BB), dim3(1024), 0, stream>>>(W_hh, b_hh, out);
}